// Round 8
// baseline (332.090 us; speedup 1.0000x reference)
//
#include <hip/hip_runtime.h>

#define BB 32
#define LL 4096
#define DD 512
#define NUM 32
#define KK 5

typedef float f32x4 __attribute__((ext_vector_type(4)));

// lags = trunc(linspace(1, 168, 32)) -- precomputed, verified margins >= 0.03
__device__ __constant__ int d_LAGS[NUM] = {
    1, 6, 11, 17, 22, 27, 33, 38, 44, 49, 54, 60, 65, 71, 76, 81,
    87, 92, 97, 103, 108, 114, 119, 124, 130, 135, 141, 146, 151, 157, 162, 168};

// ---------------- Kernel 1: row means over D ----------------
// One wave (64 lanes) per row; 4 rows per 256-thread block.
// Regular (caching) loads on purpose: this pass keeps x resident in L3
// (x = 256 MiB = Infinity Cache capacity) for the combine pass's gathers.
__global__ __launch_bounds__(256) void k_mean(const float* __restrict__ x,
                                              float* __restrict__ xm) {
    int row  = blockIdx.x * 4 + (threadIdx.x >> 6);   // [0, B*L)
    int lane = threadIdx.x & 63;
    const float* p = x + (size_t)row * DD;
    f32x4 a = *reinterpret_cast<const f32x4*>(p + 4 * lane);
    f32x4 b = *reinterpret_cast<const f32x4*>(p + 4 * lane + 256);
    float s = (a.x + a.y) + (a.z + a.w) + (b.x + b.y) + (b.z + b.w);
#pragma unroll
    for (int off = 32; off > 0; off >>= 1) s += __shfl_down(s, off, 64);
    if (lane == 0) xm[row] = s * (1.0f / DD);
}

// ---------------- Kernel 2: autocorrelation scores ----------------
// One block per (batch, lag-candidate); 1024 blocks -> enough TLP to hide
// global-load latency (R4 lesson: low-block-count versions are latency-bound).
__global__ __launch_bounds__(256) void k_scores(const float* __restrict__ xm,
                                                float* __restrict__ scores) {
    int b   = blockIdx.x >> 5;   // / NUM
    int k   = blockIdx.x & 31;   // % NUM
    int lag = d_LAGS[k];
    const float* row = xm + b * LL;
    int n = LL - lag;
    float s = 0.0f;
    for (int t = threadIdx.x; t < n; t += 256) s += row[t] * row[t + lag];
#pragma unroll
    for (int off = 32; off > 0; off >>= 1) s += __shfl_down(s, off, 64);
    __shared__ float red[4];
    int wid = threadIdx.x >> 6, lane = threadIdx.x & 63;
    if (lane == 0) red[wid] = s;
    __syncthreads();
    if (threadIdx.x == 0) {
        float tot = (red[0] + red[1]) + (red[2] + red[3]);
        scores[blockIdx.x] = tot / (float)n;
    }
}

// ---------------- Kernel 3: weighted sum of 5 rolls (+inline top-5) --------
// 256-thread block = 2 consecutive output rows (b,t),(b,t+1); thread handles a
// float4 at d = 4*(tid&127). XCD-contiguous swizzle: each of the 8 XCDs owns
// 16384 consecutive rows (= 4 whole batches), so the 5 lagged source rows
// (span <= 168 rows = 336 KB) stay in that XCD's L2.
// Top-5 + weights are recomputed redundantly by EVERY thread from the 32
// scores (broadcast loads, uniform ~200-op chain, deterministic -> identical
// in all blocks). Replaces the separate 1-block k_topk launch and the LDS
// staging + __syncthreads the R5 combine needed.
// Output stores NON-TEMPORAL: bypass L2/L3 so x stays L3-resident across
// passes and graph replays (confirmed R6/R7: FETCH ~ 273 MB = x read once).
__global__ __launch_bounds__(256) void k_combine(const float* __restrict__ x,
                                                 const float* __restrict__ scores,
                                                 float* __restrict__ out) {
    unsigned bid = blockIdx.x;                          // [0, B*L/2)
    const unsigned PAIRS_PER_XCD = (BB * LL / 2) / 8;   // 8192
    unsigned pid = (bid & 7u) * PAIRS_PER_XCD + (bid >> 3);
    unsigned r   = pid * 2 + (threadIdx.x >> 7);        // output row [0, B*L)
    int b = (int)(r >> 12);      // / 4096
    int t = (int)(r & 4095u);    // % 4096

    // --- inline top-5 (tie-break smallest index = lax.top_k semantics) ---
    float v[NUM];
#pragma unroll
    for (int i = 0; i < NUM; i++) v[i] = scores[b * NUM + i];
    float ww[KK];
    int   lg[KK];
    float sum = 0.0f;
#pragma unroll
    for (int j = 0; j < KK; j++) {
        float best = -INFINITY;
        int bi = 0;
#pragma unroll
        for (int i = 0; i < NUM; i++) {
            if (v[i] > best) { best = v[i]; bi = i; }
        }
        ww[j] = best;
        lg[j] = d_LAGS[bi];
        v[bi] = -INFINITY;
        sum  += best;
    }
    float den = sum + 1e-6f;
#pragma unroll
    for (int j = 0; j < KK; j++) ww[j] = ww[j] / den;   // same op order as reference

    const float* xb = x + (size_t)b * (LL * DD);
    int d4 = threadIdx.x & 127;
    f32x4 acc = {0.f, 0.f, 0.f, 0.f};
#pragma unroll
    for (int j = 0; j < KK; j++) {
        int src = (t - lg[j]) & (LL - 1);   // roll(+lag): out[t] = x[(t-lag) mod L]
        f32x4 vv = *reinterpret_cast<const f32x4*>(xb + (size_t)src * DD + 4 * d4);
        float wj = ww[j];
        acc.x += wj * vv.x;
        acc.y += wj * vv.y;
        acc.z += wj * vv.z;
        acc.w += wj * vv.w;
    }
    __builtin_nontemporal_store(acc,
        reinterpret_cast<f32x4*>(out + (size_t)r * DD + 4 * d4));
}

extern "C" void kernel_launch(void* const* d_in, const int* in_sizes, int n_in,
                              void* d_out, int out_size, void* d_ws, size_t ws_size,
                              hipStream_t stream) {
    const float* x = (const float*)d_in[0];
    float* out = (float*)d_out;

    // workspace layout (all fp32, < 1 MB total)
    char* ws = (char*)d_ws;
    float* xm     = (float*)(ws);                         // B*L floats   = 512 KB
    float* scores = (float*)(ws + (size_t)BB * LL * 4);   // B*NUM floats = 4 KB

    k_mean<<<(BB * LL) / 4, 256, 0, stream>>>(x, xm);
    k_scores<<<BB * NUM, 256, 0, stream>>>(xm, scores);
    k_combine<<<(BB * LL) / 2, 256, 0, stream>>>(x, scores, out);
}

// Round 9
// 326.265 us; speedup vs baseline: 1.0179x; 1.0179x over previous
//
#include <hip/hip_runtime.h>

#define BB 32
#define LL 4096
#define DD 512
#define NUM 32
#define KK 5

typedef float f32x4 __attribute__((ext_vector_type(4)));

// lags = trunc(linspace(1, 168, 32)) -- precomputed, verified margins >= 0.03
__device__ __constant__ int d_LAGS[NUM] = {
    1, 6, 11, 17, 22, 27, 33, 38, 44, 49, 54, 60, 65, 71, 76, 81,
    87, 92, 97, 103, 108, 114, 119, 124, 130, 135, 141, 146, 151, 157, 162, 168};

// ---------------- Kernel 1: row means over D ----------------
// One wave (64 lanes) per row; 4 rows per 256-thread block.
// Regular (caching) loads on purpose: this pass keeps x resident in L3
// (x = 256 MiB = Infinity Cache capacity) for the combine pass's gathers.
__global__ __launch_bounds__(256) void k_mean(const float* __restrict__ x,
                                              float* __restrict__ xm) {
    int row  = blockIdx.x * 4 + (threadIdx.x >> 6);   // [0, B*L)
    int lane = threadIdx.x & 63;
    const float* p = x + (size_t)row * DD;
    f32x4 a = *reinterpret_cast<const f32x4*>(p + 4 * lane);
    f32x4 b = *reinterpret_cast<const f32x4*>(p + 4 * lane + 256);
    float s = (a.x + a.y) + (a.z + a.w) + (b.x + b.y) + (b.z + b.w);
#pragma unroll
    for (int off = 32; off > 0; off >>= 1) s += __shfl_down(s, off, 64);
    if (lane == 0) xm[row] = s * (1.0f / DD);
}

// ---------------- Kernel 2: autocorrelation scores ----------------
// One block per (batch, lag-candidate); 1024 blocks -> enough TLP to hide
// global-load latency (R4 lesson: low-block-count versions are latency-bound).
__global__ __launch_bounds__(256) void k_scores(const float* __restrict__ xm,
                                                float* __restrict__ scores) {
    int b   = blockIdx.x >> 5;   // / NUM
    int k   = blockIdx.x & 31;   // % NUM
    int lag = d_LAGS[k];
    const float* row = xm + b * LL;
    int n = LL - lag;
    float s = 0.0f;
    for (int t = threadIdx.x; t < n; t += 256) s += row[t] * row[t + lag];
#pragma unroll
    for (int off = 32; off > 0; off >>= 1) s += __shfl_down(s, off, 64);
    __shared__ float red[4];
    int wid = threadIdx.x >> 6, lane = threadIdx.x & 63;
    if (lane == 0) red[wid] = s;
    __syncthreads();
    if (threadIdx.x == 0) {
        float tot = (red[0] + red[1]) + (red[2] + red[3]);
        scores[blockIdx.x] = tot / (float)n;
    }
}

// ---------------- Kernel 3: weighted sum of 5 rolls (+inline top-5) --------
// 256-thread block = 2 consecutive output rows; thread handles a float4 at
// d = 4*(tid&127). XCD-contiguous swizzle: each of the 8 XCDs owns 16384
// consecutive rows (= 4 whole batches) -> lagged source rows stay in its L2.
// Top-5 recomputed redundantly by EVERY thread. R8 lesson (rule #20): the
// "remove selected" step must be compile-time indexed — v[bi]=-INF with
// runtime bi sent v[32] to scratch (312 us, VGPR=24). Now an unrolled
// cndmask chain keeps v[] in VGPRs.
// Output stores NON-TEMPORAL: bypass L2/L3 so x stays L3-resident across
// passes and graph replays (confirmed R6/R7: FETCH ~ 273 MB = x read once).
__global__ __launch_bounds__(256) void k_combine(const float* __restrict__ x,
                                                 const float* __restrict__ scores,
                                                 float* __restrict__ out) {
    unsigned bid = blockIdx.x;                          // [0, B*L/2)
    const unsigned PAIRS_PER_XCD = (BB * LL / 2) / 8;   // 8192
    unsigned pid = (bid & 7u) * PAIRS_PER_XCD + (bid >> 3);
    unsigned r   = pid * 2 + (threadIdx.x >> 7);        // output row [0, B*L)
    int b = (int)(r >> 12);      // / 4096
    int t = (int)(r & 4095u);    // % 4096

    // --- inline top-5 (tie-break smallest index = lax.top_k semantics) ---
    float v[NUM];
#pragma unroll
    for (int i = 0; i < NUM; i++) v[i] = scores[b * NUM + i];
    float ww[KK];
    int   lg[KK];
    float sum = 0.0f;
#pragma unroll
    for (int j = 0; j < KK; j++) {
        float best = -INFINITY;
        int bi = 0;
#pragma unroll
        for (int i = 0; i < NUM; i++) {
            if (v[i] > best) { best = v[i]; bi = i; }
        }
        ww[j] = best;
        lg[j] = d_LAGS[bi];
        sum  += best;
        // compile-time indices only: cndmask chain, v[] stays in VGPRs
#pragma unroll
        for (int i = 0; i < NUM; i++) v[i] = (i == bi) ? -INFINITY : v[i];
    }
    float den = sum + 1e-6f;
#pragma unroll
    for (int j = 0; j < KK; j++) ww[j] = ww[j] / den;   // same op order as reference

    const float* xb = x + (size_t)b * (LL * DD);
    int d4 = threadIdx.x & 127;
    f32x4 acc = {0.f, 0.f, 0.f, 0.f};
#pragma unroll
    for (int j = 0; j < KK; j++) {
        int src = (t - lg[j]) & (LL - 1);   // roll(+lag): out[t] = x[(t-lag) mod L]
        f32x4 vv = *reinterpret_cast<const f32x4*>(xb + (size_t)src * DD + 4 * d4);
        float wj = ww[j];
        acc.x += wj * vv.x;
        acc.y += wj * vv.y;
        acc.z += wj * vv.z;
        acc.w += wj * vv.w;
    }
    __builtin_nontemporal_store(acc,
        reinterpret_cast<f32x4*>(out + (size_t)r * DD + 4 * d4));
}

extern "C" void kernel_launch(void* const* d_in, const int* in_sizes, int n_in,
                              void* d_out, int out_size, void* d_ws, size_t ws_size,
                              hipStream_t stream) {
    const float* x = (const float*)d_in[0];
    float* out = (float*)d_out;

    // workspace layout (all fp32, < 1 MB total)
    char* ws = (char*)d_ws;
    float* xm     = (float*)(ws);                         // B*L floats   = 512 KB
    float* scores = (float*)(ws + (size_t)BB * LL * 4);   // B*NUM floats = 4 KB

    k_mean<<<(BB * LL) / 4, 256, 0, stream>>>(x, xm);
    k_scores<<<BB * NUM, 256, 0, stream>>>(xm, scores);
    k_combine<<<(BB * LL) / 2, 256, 0, stream>>>(x, scores, out);
}

// Round 10
// 172.347 us; speedup vs baseline: 1.9269x; 1.8931x over previous
//
#include <hip/hip_runtime.h>

#define BB 32
#define LL 4096
#define DD 512
#define NUM 32
#define KK 5

typedef float f32x4 __attribute__((ext_vector_type(4)));

// lags = trunc(linspace(1, 168, 32)) -- precomputed, verified margins >= 0.03
__device__ __constant__ int d_LAGS[NUM] = {
    1, 6, 11, 17, 22, 27, 33, 38, 44, 49, 54, 60, 65, 71, 76, 81,
    87, 92, 97, 103, 108, 114, 119, 124, 130, 135, 141, 146, 151, 157, 162, 168};

// ---------------- Kernel 1: row means over D ----------------
// One wave (64 lanes) per row; 4 rows per 256-thread block.
// Regular (caching) loads on purpose: this pass keeps x resident in L3
// (x = 256 MiB = Infinity Cache capacity) for the combine pass's gathers.
__global__ __launch_bounds__(256) void k_mean(const float* __restrict__ x,
                                              float* __restrict__ xm) {
    int row  = blockIdx.x * 4 + (threadIdx.x >> 6);   // [0, B*L)
    int lane = threadIdx.x & 63;
    const float* p = x + (size_t)row * DD;
    f32x4 a = *reinterpret_cast<const f32x4*>(p + 4 * lane);
    f32x4 b = *reinterpret_cast<const f32x4*>(p + 4 * lane + 256);
    float s = (a.x + a.y) + (a.z + a.w) + (b.x + b.y) + (b.z + b.w);
#pragma unroll
    for (int off = 32; off > 0; off >>= 1) s += __shfl_down(s, off, 64);
    if (lane == 0) xm[row] = s * (1.0f / DD);
}

// ---------------- Kernel 2: autocorrelation scores ----------------
// One block per (batch, lag-candidate); 1024 blocks -> enough TLP to hide
// global-load latency (R4 lesson: low-block-count versions are latency-bound).
__global__ __launch_bounds__(256) void k_scores(const float* __restrict__ xm,
                                                float* __restrict__ scores) {
    int b   = blockIdx.x >> 5;   // / NUM
    int k   = blockIdx.x & 31;   // % NUM
    int lag = d_LAGS[k];
    const float* row = xm + b * LL;
    int n = LL - lag;
    float s = 0.0f;
    for (int t = threadIdx.x; t < n; t += 256) s += row[t] * row[t + lag];
#pragma unroll
    for (int off = 32; off > 0; off >>= 1) s += __shfl_down(s, off, 64);
    __shared__ float red[4];
    int wid = threadIdx.x >> 6, lane = threadIdx.x & 63;
    if (lane == 0) red[wid] = s;
    __syncthreads();
    if (threadIdx.x == 0) {
        float tot = (red[0] + red[1]) + (red[2] + red[3]);
        scores[blockIdx.x] = tot / (float)n;
    }
}

// ---------------- Kernel 3: weighted sum of 5 rolls (+wave topk) ----------
// 256-thread block = 2 consecutive output rows; thread handles a float4 at
// d = 4*(tid&127). XCD-contiguous swizzle: each of the 8 XCDs owns 16384
// consecutive rows (= 4 whole batches) -> lagged source rows stay in its L2.
//
// Top-5: computed ONCE per block by wave 0, wave-parallel (R9 lesson: the
// per-thread redundant chain was ~800 VALU ops x 16.7M threads = VALU-issue
// bound, 306 us). Lane i<32 holds score i; argmax via 5-step shfl_xor
// butterfly carrying (val,idx), min-idx on ties (= lax.top_k first-occurrence
// semantics); winner knocked out by per-lane compare (no runtime indexing).
// ~350 issue-cycles per block, hidden under the gathers.
//
// Output stores NON-TEMPORAL: bypass caches so x stays L3-resident across
// passes and graph replays (confirmed R6/R7: FETCH ~ 273 MB = x read once).
__global__ __launch_bounds__(256) void k_combine(const float* __restrict__ x,
                                                 const float* __restrict__ scores,
                                                 float* __restrict__ out) {
    unsigned bid = blockIdx.x;                          // [0, B*L/2)
    const unsigned PAIRS_PER_XCD = (BB * LL / 2) / 8;   // 8192
    unsigned pid = (bid & 7u) * PAIRS_PER_XCD + (bid >> 3);
    unsigned r   = pid * 2 + (threadIdx.x >> 7);        // output row [0, B*L)
    int b = (int)(r >> 12);      // / 4096
    int t = (int)(r & 4095u);    // % 4096

    __shared__ float ww_s[KK];
    __shared__ int   lg_s[KK];

    int tid = threadIdx.x;
    if (tid < 64) {              // wave 0 only
        int lane  = tid;                         // 0..63
        float myv = (lane < NUM) ? scores[b * NUM + lane] : -INFINITY;
        int   myi = lane;
        float vals[KK];
        int   lgs[KK];
        float sum = 0.0f;
#pragma unroll
        for (int j = 0; j < KK; ++j) {
            float v  = myv;
            int   ix = myi;
#pragma unroll
            for (int off = 16; off > 0; off >>= 1) {
                float ov = __shfl_xor(v, off, 32);
                int   oi = __shfl_xor(ix, off, 32);
                bool take = (ov > v) || (ov == v && oi < ix);
                v  = take ? ov : v;
                ix = take ? oi : ix;
            }
            vals[j] = v;         // all lanes 0..31 converge to (max, min-idx)
            lgs[j]  = ix;
            sum    += v;
            myv = (myi == ix) ? -INFINITY : myv;   // knock out winner
        }
        if (lane == 0) {
            float den = sum + 1e-6f;
#pragma unroll
            for (int j = 0; j < KK; ++j) {
                ww_s[j] = vals[j] / den;           // same op order as reference
                lg_s[j] = d_LAGS[lgs[j]];
            }
        }
    }
    __syncthreads();

    float ww[KK];
    int   lg[KK];
#pragma unroll
    for (int j = 0; j < KK; ++j) {
        ww[j] = ww_s[j];
        lg[j] = lg_s[j];
    }

    const float* xb = x + (size_t)b * (LL * DD);
    int d4 = threadIdx.x & 127;
    f32x4 acc = {0.f, 0.f, 0.f, 0.f};
#pragma unroll
    for (int j = 0; j < KK; j++) {
        int src = (t - lg[j]) & (LL - 1);   // roll(+lag): out[t] = x[(t-lag) mod L]
        f32x4 vv = *reinterpret_cast<const f32x4*>(xb + (size_t)src * DD + 4 * d4);
        float wj = ww[j];
        acc.x += wj * vv.x;
        acc.y += wj * vv.y;
        acc.z += wj * vv.z;
        acc.w += wj * vv.w;
    }
    __builtin_nontemporal_store(acc,
        reinterpret_cast<f32x4*>(out + (size_t)r * DD + 4 * d4));
}

extern "C" void kernel_launch(void* const* d_in, const int* in_sizes, int n_in,
                              void* d_out, int out_size, void* d_ws, size_t ws_size,
                              hipStream_t stream) {
    const float* x = (const float*)d_in[0];
    float* out = (float*)d_out;

    // workspace layout (all fp32, < 1 MB total)
    char* ws = (char*)d_ws;
    float* xm     = (float*)(ws);                         // B*L floats   = 512 KB
    float* scores = (float*)(ws + (size_t)BB * LL * 4);   // B*NUM floats = 4 KB

    k_mean<<<(BB * LL) / 4, 256, 0, stream>>>(x, xm);
    k_scores<<<BB * NUM, 256, 0, stream>>>(xm, scores);
    k_combine<<<(BB * LL) / 2, 256, 0, stream>>>(x, scores, out);
}

// Round 11
// 134.446 us; speedup vs baseline: 2.4701x; 1.2819x over previous
//
#include <hip/hip_runtime.h>

#define BB 32
#define LL 4096
#define DD 512
#define NUM 32
#define KK 5
#define RPB 4   // row-PAIRS per combine block (8 rows, never crosses a batch)

typedef float f32x4 __attribute__((ext_vector_type(4)));

// lags = trunc(linspace(1, 168, 32)) -- precomputed, verified margins >= 0.03
__device__ __constant__ int d_LAGS[NUM] = {
    1, 6, 11, 17, 22, 27, 33, 38, 44, 49, 54, 60, 65, 71, 76, 81,
    87, 92, 97, 103, 108, 114, 119, 124, 130, 135, 141, 146, 151, 157, 162, 168};

// ---------------- Kernel 1: row means over D ----------------
// One wave (64 lanes) per row; 4 rows per 256-thread block.
// Regular (caching) loads on purpose: populates L3 with x for combine.
__global__ __launch_bounds__(256) void k_mean(const float* __restrict__ x,
                                              float* __restrict__ xm) {
    int row  = blockIdx.x * 4 + (threadIdx.x >> 6);   // [0, B*L)
    int lane = threadIdx.x & 63;
    const float* p = x + (size_t)row * DD;
    f32x4 a = *reinterpret_cast<const f32x4*>(p + 4 * lane);
    f32x4 b = *reinterpret_cast<const f32x4*>(p + 4 * lane + 256);
    float s = (a.x + a.y) + (a.z + a.w) + (b.x + b.y) + (b.z + b.w);
#pragma unroll
    for (int off = 32; off > 0; off >>= 1) s += __shfl_down(s, off, 64);
    if (lane == 0) xm[row] = s * (1.0f / DD);
}

// ---------------- Kernel 2: autocorrelation scores ----------------
// One block per (batch, lag-candidate); 1024 blocks -> enough TLP to hide
// global-load latency (R4 lesson: low-block-count versions are latency-bound).
__global__ __launch_bounds__(256) void k_scores(const float* __restrict__ xm,
                                                float* __restrict__ scores) {
    int b   = blockIdx.x >> 5;   // / NUM
    int k   = blockIdx.x & 31;   // % NUM
    int lag = d_LAGS[k];
    const float* row = xm + b * LL;
    int n = LL - lag;
    float s = 0.0f;
    for (int t = threadIdx.x; t < n; t += 256) s += row[t] * row[t + lag];
#pragma unroll
    for (int off = 32; off > 0; off >>= 1) s += __shfl_down(s, off, 64);
    __shared__ float red[4];
    int wid = threadIdx.x >> 6, lane = threadIdx.x & 63;
    if (lane == 0) red[wid] = s;
    __syncthreads();
    if (threadIdx.x == 0) {
        float tot = (red[0] + red[1]) + (red[2] + red[3]);
        scores[blockIdx.x] = tot / (float)n;
    }
}

// ---------------- Kernel 3: per-batch top-5 + weights ----------------
// One thread per batch (B=32), ONE block total. 4 us launch is cheaper than
// any inlining attempt (R8: scratch 312us; R9: VALU-issue 306us; R10:
// per-block prologue tax +38us). Tie-break smallest index (lax.top_k).
__global__ __launch_bounds__(64) void k_topk(const float* __restrict__ scores,
                                             float* __restrict__ w,
                                             int* __restrict__ sel) {
    int b = threadIdx.x;
    if (b >= BB) return;
    float sc[NUM];
#pragma unroll
    for (int i = 0; i < NUM; i++) sc[i] = scores[b * NUM + i];
    float vals[KK];
    int idx[KK];
#pragma unroll
    for (int j = 0; j < KK; j++) {
        float best = -INFINITY;
        int bi = 0;
#pragma unroll
        for (int i = 0; i < NUM; i++) {
            if (sc[i] > best) { best = sc[i]; bi = i; }
        }
        vals[j] = best;
        idx[j]  = bi;
        sc[bi]  = -INFINITY;
    }
    float sum = 0.0f;
#pragma unroll
    for (int j = 0; j < KK; j++) sum += vals[j];
    float den = sum + 1e-6f;
#pragma unroll
    for (int j = 0; j < KK; j++) {
        w[b * KK + j]   = vals[j] / den;
        sel[b * KK + j] = d_LAGS[idx[j]];
    }
}

// ---------------- Kernel 4: weighted sum of 5 rolls ----------------
// R11 change vs R5: each 256-thread block handles RPB=4 consecutive row-pairs
// (8 rows) -> 8192 blocks. Amortizes the weights-stage prologue 4x, keeps 4
// NT stores + up to 20 gathers in flight per thread, 8x fewer dispatches.
// XCD-contiguous swizzle at quad granularity: each XCD owns 1024 consecutive
// quads = 2 whole batches -> lagged source rows (span <=168 rows) stay in L2.
// Output stores NON-TEMPORAL: bypass caches so x stays L3-resident (R6/R7:
// FETCH ~273 MB/replay = x read from HBM once).
__global__ __launch_bounds__(256) void k_combine(const float* __restrict__ x,
                                                 const float* __restrict__ w,
                                                 const int* __restrict__ sel,
                                                 float* __restrict__ out) {
    unsigned bid = blockIdx.x;                            // [0, 8192)
    const unsigned GRP_PER_XCD = (BB * LL / 2 / RPB) / 8; // 1024
    unsigned gid   = (bid & 7u) * GRP_PER_XCD + (bid >> 3);
    unsigned pair0 = gid * RPB;                           // first row-pair
    unsigned r0    = pair0 * 2;                           // first row (mult of 8)
    int b = (int)(r0 >> 12);     // batch (8-row group never crosses boundary)

    __shared__ float ww[KK];
    __shared__ int   llag[KK];
    if (threadIdx.x < KK) {
        ww[threadIdx.x]   = w[b * KK + threadIdx.x];
        llag[threadIdx.x] = sel[b * KK + threadIdx.x];
    }
    __syncthreads();

    float wreg[KK];
    int   lreg[KK];
#pragma unroll
    for (int j = 0; j < KK; j++) { wreg[j] = ww[j]; lreg[j] = llag[j]; }

    const float* xb = x + (size_t)b * (LL * DD);
    float* ob = out + (size_t)b * (LL * DD);
    const int half = threadIdx.x >> 7;   // 0..1
    const int d4   = threadIdx.x & 127;
    const int t0   = (int)(r0 & 4095u);  // local row of first pair

#pragma unroll
    for (int i = 0; i < RPB; i++) {
        int t = t0 + i * 2 + half;       // local row in [0, 4096)
        f32x4 acc = {0.f, 0.f, 0.f, 0.f};
#pragma unroll
        for (int j = 0; j < KK; j++) {
            int src = (t - lreg[j]) & (LL - 1);   // roll(+lag)
            f32x4 v = *reinterpret_cast<const f32x4*>(xb + (size_t)src * DD + 4 * d4);
            float wj = wreg[j];
            acc.x += wj * v.x;
            acc.y += wj * v.y;
            acc.z += wj * v.z;
            acc.w += wj * v.w;
        }
        __builtin_nontemporal_store(acc,
            reinterpret_cast<f32x4*>(ob + (size_t)t * DD + 4 * d4));
    }
}

extern "C" void kernel_launch(void* const* d_in, const int* in_sizes, int n_in,
                              void* d_out, int out_size, void* d_ws, size_t ws_size,
                              hipStream_t stream) {
    const float* x = (const float*)d_in[0];
    float* out = (float*)d_out;

    // workspace layout (all fp32/int32, < 1 MB total)
    char* ws = (char*)d_ws;
    float* xm     = (float*)(ws);                         // B*L floats   = 512 KB
    float* scores = (float*)(ws + (size_t)BB * LL * 4);   // B*NUM floats = 4 KB
    float* wts    = (float*)(ws + (size_t)BB * LL * 4 + BB * NUM * 4);        // B*K
    int*   sel    = (int*)  (ws + (size_t)BB * LL * 4 + BB * NUM * 4 + BB * KK * 4);

    k_mean<<<(BB * LL) / 4, 256, 0, stream>>>(x, xm);
    k_scores<<<BB * NUM, 256, 0, stream>>>(xm, scores);
    k_topk<<<1, 64, 0, stream>>>(scores, wts, sel);
    k_combine<<<(BB * LL) / (2 * RPB), 256, 0, stream>>>(x, wts, sel, out);
}